// Round 6
// baseline (143.531 us; speedup 1.0000x reference)
//
#include <hip/hip_runtime.h>
#include <hip/hip_cooperative_groups.h>
#include <stdint.h>

namespace cg = cooperative_groups;

#define NN 8192
#define NE 8192
#define DIM 256
#define NW 128   // 64-bit words per adjacency row (8192 bits)
#define HCAP 64  // max common neighbors; worst case i==j -> deg_max ~55
#define TE 32    // edges per block
#define NBLK 256 // cooperative grid: 1 block/CU

typedef short bf16x8 __attribute__((ext_vector_type(8)));
typedef float f32x4 __attribute__((ext_vector_type(4)));

__device__ __forceinline__ unsigned short f2bf(float f) {
  uint32_t u = __builtin_bit_cast(uint32_t, f);
  u += 0x7fffu + ((u >> 16) & 1u);   // round-to-nearest-even
  return (unsigned short)(u >> 16);
}
__device__ __forceinline__ float bf2f(unsigned short h) {
  uint32_t u = ((uint32_t)h) << 16;
  return __builtin_bit_cast(float, u);
}

#define LDP 264  // 256 + 8 bf16 pad (row stride 528 B, 2-way bank alias = free)

__device__ __forceinline__ void load_w(const unsigned short* __restrict__ Wt,
                                       bf16x8 w[2][8], int lane, int wave) {
  const int lr = lane & 15;
  const int kl = (lane >> 4) * 8;
  const int n0 = wave * 32;
#pragma unroll
  for (int kk = 0; kk < 8; ++kk) {
    const int k0 = kk * 32 + kl;
    w[0][kk] = *(const bf16x8*)(Wt + (size_t)(n0 + lr) * DIM + k0);
    w[1][kk] = *(const bf16x8*)(Wt + (size_t)(n0 + 16 + lr) * DIM + k0);
  }
}

__device__ __forceinline__ void gemm_reg(const unsigned short (*src)[LDP],
                                         const bf16x8 w[2][8],
                                         f32x4 acc[2][2], int lane) {
  const int lr = lane & 15;
  const int kl = (lane >> 4) * 8;
#pragma unroll
  for (int kk = 0; kk < 8; ++kk) {
    const int k0 = kk * 32 + kl;
    bf16x8 a0 = *(const bf16x8*)(&src[lr][k0]);
    bf16x8 a1 = *(const bf16x8*)(&src[16 + lr][k0]);
    acc[0][0] = __builtin_amdgcn_mfma_f32_16x16x32_bf16(a0, w[0][kk], acc[0][0], 0, 0, 0);
    acc[0][1] = __builtin_amdgcn_mfma_f32_16x16x32_bf16(a0, w[1][kk], acc[0][1], 0, 0, 0);
    acc[1][0] = __builtin_amdgcn_mfma_f32_16x16x32_bf16(a1, w[0][kk], acc[1][0], 0, 0, 0);
    acc[1][1] = __builtin_amdgcn_mfma_f32_16x16x32_bf16(a1, w[1][kk], acc[1][1], 0, 0, 0);
  }
}

__device__ __forceinline__ void zero22(f32x4 a[2][2]) {
#pragma unroll
  for (int m = 0; m < 2; ++m)
#pragma unroll
    for (int n = 0; n < 2; ++n) {
      f32x4 z = {0.f, 0.f, 0.f, 0.f};
      a[m][n] = z;
    }
}

__device__ __forceinline__ void epilogue32(f32x4 acc[2][2], float bb0, float bb1,
                                           bool relu, unsigned short (*dst)[LDP],
                                           int lane, int wave) {
  const int lc = lane & 15;
  const int rg = (lane >> 4) * 4;
#pragma unroll
  for (int n = 0; n < 2; ++n) {
    const int col = wave * 32 + n * 16 + lc;
    const float bb = n ? bb1 : bb0;
#pragma unroll
    for (int m = 0; m < 2; ++m)
#pragma unroll
      for (int q = 0; q < 4; ++q) {
        float v = acc[m][n][q] + bb;
        if (relu) v = fmaxf(v, 0.f);
        dst[m * 16 + rg + q][col] = f2bf(v);
      }
  }
}

// ==================== single cooperative kernel ====================
// Pre-sync : adj pack (1/256th per block) + xixj->lC + W transpose + preloads
// grid.sync
// Post-sync: bits intersect + xcn->lA + 6-GEMM chain (reg-prefetched W) + GEMV
//
// Pack bit layout: task t = row r*32 + segment s. Lane l loads float4 at cols
// s*256+4l..4l+3; ballot(comp q) -> bits[r*128+s*4+q], bit l <-> col s*256+4l+q.
__global__ __launch_bounds__(512, 2) void coop_kernel(
    const float* __restrict__ x,
    const float* __restrict__ adj,
    const int* __restrict__ tar,
    const float* __restrict__ W1c, const float* __restrict__ W2c,
    const float* __restrict__ W1j, const float* __restrict__ W2j,
    const float* __restrict__ Wl1, const float* __restrict__ Wl2,
    const float* __restrict__ b1c, const float* __restrict__ b2c,
    const float* __restrict__ b1j, const float* __restrict__ b2j,
    const float* __restrict__ bl1, const float* __restrict__ bl2,
    const float* __restrict__ Wout, const float* __restrict__ bout,
    unsigned short* __restrict__ Wt,
    unsigned long long* __restrict__ bits,
    float* __restrict__ out) {
  __shared__ unsigned short lA[TE][LDP];  // xcn -> U2 -> h2
  __shared__ unsigned short lB[TE][LDP];  // U1 -> h -> h3
  __shared__ unsigned short lC[TE][LDP];  // xixj
  __shared__ int hits[TE][HCAP];
  __shared__ int nh[TE];

  const int tid = threadIdx.x;
  const int lane = tid & 63;
  const int wave = tid >> 6;
  const int blk = blockIdx.x;
  const int e0 = blk * TE;

  if (tid < TE) nh[tid] = 0;

  // ---- per-lane constant preloads (biases, Wout) ----
  const int lc = lane & 15;
  const int c0 = wave * 32 + lc;
  const int c1 = c0 + 16;
  const float vb1c0 = b1c[c0], vb1c1 = b1c[c1];
  const float vb1j0 = b1j[c0], vb1j1 = b1j[c1];
  const float vb20 = b2c[c0] + b2j[c0], vb21 = b2c[c1] + b2j[c1];
  const float vbl10 = bl1[c0], vbl11 = bl1[c1];
  const float vbl20 = bl2[c0], vbl21 = bl2[c1];
  const int gpart = tid & 15;  // GEMV: 16 threads/edge
  float wv[16];
#pragma unroll
  for (int q = 0; q < 16; ++q) wv[q] = Wout[gpart * 16 + q];
  const float vbout = bout[0];

  // ---- pre-sync (1): xixj -> lC ----
  {
    const int col = tid & 255;
    const int sub = tid >> 8;  // 0/1 -> 16 edges each
    float vi[16], vj[16];
#pragma unroll
    for (int p = 0; p < 16; ++p) {
      const int e = sub * 16 + p;
      vi[p] = x[(size_t)tar[e0 + e] * DIM + col];
      vj[p] = x[(size_t)tar[NE + e0 + e] * DIM + col];
    }
#pragma unroll
    for (int p = 0; p < 16; ++p)
      lC[sub * 16 + p][col] = f2bf(vi[p] * vj[p]);
  }

  // ---- pre-sync (2): weight transpose share ----
  // 6*65536 elems / (256 blk * 512 thr) = 3 per thread. Coalesced W read,
  // scattered bf16 Wt write (stores don't stall).
  {
    const int gid = blk * 512 + tid;
#pragma unroll
    for (int r = 0; r < 3; ++r) {
      const int eid = gid + r * 131072;
      const int w = eid >> 16;
      const int rem = eid & 65535;   // = k*256 + n
      const int k = rem >> 8;
      const int n = rem & 255;
      const float* W = (w < 1) ? W1c : (w < 2) ? W2c : (w < 3) ? W1j
                     : (w < 4) ? W2j : (w < 5) ? Wl1 : Wl2;
      Wt[w * 65536 + n * DIM + k] = f2bf(W[rem]);
    }
  }

  // ---- pre-sync (3): adj pack, 1024 float4-tasks per block, 2-deep pipe ----
  {
    const float4* __restrict__ adjv = (const float4*)adj;
    const int base = blk * 1024;
    int tt = wave * 2;
    float4 v0 = adjv[(size_t)((base + tt) >> 5) * 2048 + ((base + tt) & 31) * 64 + lane];
    float4 v1 = adjv[(size_t)((base + tt + 1) >> 5) * 2048 + ((base + tt + 1) & 31) * 64 + lane];
    for (; tt < 1024; tt += 16) {
      const int t = base + tt;
      const int tn = (tt + 16 < 1024) ? base + tt + 16 : base;  // dummy tail
      float4 p0v = adjv[(size_t)(tn >> 5) * 2048 + (tn & 31) * 64 + lane];
      float4 p1v = adjv[(size_t)((tn + 1) >> 5) * 2048 + ((tn + 1) & 31) * 64 + lane];
      unsigned long long m0 = __ballot(v0.x != 0.0f);
      unsigned long long m1 = __ballot(v0.y != 0.0f);
      unsigned long long m2 = __ballot(v0.z != 0.0f);
      unsigned long long m3 = __ballot(v0.w != 0.0f);
      unsigned long long k0 = __ballot(v1.x != 0.0f);
      unsigned long long k1 = __ballot(v1.y != 0.0f);
      unsigned long long k2 = __ballot(v1.z != 0.0f);
      unsigned long long k3 = __ballot(v1.w != 0.0f);
      if (lane == 0) {
        unsigned long long* p0 = bits + (size_t)(t >> 5) * NW + (t & 31) * 4;
        unsigned long long* p1 = bits + (size_t)((t + 1) >> 5) * NW + ((t + 1) & 31) * 4;
        p0[0] = m0; p0[1] = m1; p0[2] = m2; p0[3] = m3;
        p1[0] = k0; p1[1] = k1; p1[2] = k2; p1[3] = k3;
      }
      v0 = p0v; v1 = p1v;
    }
  }

  cg::this_grid().sync();  // bits + Wt now globally visible

  // ---- post-sync: issue S1/S2 weight prefetch first (hidden under intersect) ----
  bf16x8 wX[2][8], wY[2][8];
  load_w(Wt + 0 * 65536, wX, lane, wave);
  load_w(Wt + 1 * 65536, wY, lane, wave);

  // ---- intersect (16 thr/edge, 8 words each) ----
  {
    const int e_a = tid >> 4;
    const int t16 = tid & 15;
    const int ia = tar[e0 + e_a];
    const int ja = tar[NE + e0 + e_a];
    const unsigned long long* bi = bits + (size_t)ia * NW + t16 * 8;
    const unsigned long long* bj = bits + (size_t)ja * NW + t16 * 8;
#pragma unroll
    for (int q = 0; q < 8; ++q) {
      unsigned long long m = bi[q] & bj[q];
      const int w = t16 * 8 + q;
      const int base = (w >> 2) << 8;
      const int qq = w & 3;
      while (m) {
        int b = __builtin_ctzll(m);
        m &= m - 1;
        int idx = atomicAdd(&nh[e_a], 1);
        if (idx < HCAP) hits[e_a][idx] = base + (b << 2) + qq;  // node id
      }
    }
  }
  __syncthreads();

  // ---- xcn gathers -> lA ----
  {
    const int col = tid & 255;
    const int sub = tid >> 8;
#pragma unroll
    for (int p = 0; p < 16; ++p) {
      const int e = sub * 16 + p;
      const int n = nh[e] < HCAP ? nh[e] : HCAP;
      float xc = 0.f;
      for (int h = 0; h < n; ++h)
        xc += x[(size_t)hits[e][h] * DIM + col];
      lA[e][col] = f2bf(xc);
    }
  }
  __syncthreads();

  f32x4 acc[2][2], pAcc[2][2];

  // ---- S1: U1 = relu(xcn @ W1c + b1c) -> lB ; prefetch W1j -> wX ----
  zero22(acc);
  gemm_reg(lA, wX, acc, lane);
  load_w(Wt + 2 * 65536, wX, lane, wave);
  epilogue32(acc, vb1c0, vb1c1, true, lB, lane, wave);
  __syncthreads();

  // ---- S2: pAcc = U1 @ W2c (wY); S3: U2 = relu(xixj @ W1j) -> lA (wX) ----
  zero22(pAcc);
  gemm_reg(lB, wY, pAcc, lane);
  load_w(Wt + 3 * 65536, wY, lane, wave);  // prefetch W2j
  zero22(acc);
  gemm_reg(lC, wX, acc, lane);
  epilogue32(acc, vb1j0, vb1j1, true, lA, lane, wave);
  __syncthreads();

  // ---- S4: pAcc += U2 @ W2j (wY); h = pAcc + b2c+b2j -> lB (no relu) ----
  gemm_reg(lA, wY, pAcc, lane);
  load_w(Wt + 4 * 65536, wX, lane, wave);  // prefetch Wl1
  {
    const int rg = (lane >> 4) * 4;
#pragma unroll
    for (int n = 0; n < 2; ++n) {
      const int col = wave * 32 + n * 16 + lc;
      const float bb = n ? vb21 : vb20;
#pragma unroll
      for (int m = 0; m < 2; ++m)
#pragma unroll
        for (int q = 0; q < 4; ++q)
          lB[m * 16 + rg + q][col] = f2bf(pAcc[m][n][q] + bb);
    }
  }
  __syncthreads();

  // ---- S5: h2 = relu(h @ Wl1 + bl1) -> lA (wX) ; prefetch Wl2 -> wY ----
  zero22(acc);
  gemm_reg(lB, wX, acc, lane);
  load_w(Wt + 5 * 65536, wY, lane, wave);
  epilogue32(acc, vbl10, vbl11, true, lA, lane, wave);
  __syncthreads();

  // ---- S6: h3 = relu(h2 @ Wl2 + bl2) -> lB (wY) ----
  zero22(acc);
  gemm_reg(lA, wY, acc, lane);
  epilogue32(acc, vbl20, vbl21, true, lB, lane, wave);
  __syncthreads();

  // ---- GEMV: out = h3 @ Wout + bout (16 threads/edge, preloaded Wout) ----
  const int el = tid >> 4;
  float s = 0.f;
#pragma unroll
  for (int q = 0; q < 16; ++q)
    s += bf2f(lB[el][gpart * 16 + q]) * wv[q];
#pragma unroll
  for (int o = 8; o; o >>= 1) s += __shfl_xor(s, o);
  if (gpart == 0) out[e0 + el] = s + vbout;
}

extern "C" void kernel_launch(void* const* d_in, const int* in_sizes, int n_in,
                              void* d_out, int out_size, void* d_ws, size_t ws_size,
                              hipStream_t stream) {
  const float* x    = (const float*)d_in[0];
  const float* adj  = (const float*)d_in[1];
  const int*   tar  = (const int*)d_in[2];
  const float* W1c  = (const float*)d_in[3];
  const float* b1c  = (const float*)d_in[4];
  const float* W2c  = (const float*)d_in[5];
  const float* b2c  = (const float*)d_in[6];
  const float* W1j  = (const float*)d_in[7];
  const float* b1j  = (const float*)d_in[8];
  const float* W2j  = (const float*)d_in[9];
  const float* b2j  = (const float*)d_in[10];
  const float* Wl1  = (const float*)d_in[11];
  const float* bl1  = (const float*)d_in[12];
  const float* Wl2  = (const float*)d_in[13];
  const float* bl2  = (const float*)d_in[14];
  const float* Wout = (const float*)d_in[15];
  const float* bout = (const float*)d_in[16];

  char* ws = (char*)d_ws;
  unsigned short*     Wt   = (unsigned short*)(ws);                  // 768 KB
  unsigned long long* bits = (unsigned long long*)(ws + (1u << 20)); // 8 MB
  float* out = (float*)d_out;

  void* args[] = {
      (void*)&x, (void*)&adj, (void*)&tar,
      (void*)&W1c, (void*)&W2c, (void*)&W1j, (void*)&W2j,
      (void*)&Wl1, (void*)&Wl2,
      (void*)&b1c, (void*)&b2c, (void*)&b1j, (void*)&b2j,
      (void*)&bl1, (void*)&bl2, (void*)&Wout, (void*)&bout,
      (void*)&Wt, (void*)&bits, (void*)&out};

  hipLaunchCooperativeKernel((const void*)coop_kernel, dim3(NBLK), dim3(512),
                             args, 0, stream);
}

// Round 7
// 78.963 us; speedup vs baseline: 1.8177x; 1.8177x over previous
//
#include <hip/hip_runtime.h>
#include <stdint.h>

#define NN 8192
#define NE 8192
#define DIM 256
#define NW 128   // 64-bit words per adjacency row (8192 bits)
#define HCAP 64  // max common neighbors; worst case i==j -> deg_max ~55
#define TE 32    // edges per block (fused)

typedef short bf16x8 __attribute__((ext_vector_type(8)));
typedef float f32x4 __attribute__((ext_vector_type(4)));

__device__ __forceinline__ unsigned short f2bf(float f) {
  uint32_t u = __builtin_bit_cast(uint32_t, f);
  u += 0x7fffu + ((u >> 16) & 1u);   // round-to-nearest-even
  return (unsigned short)(u >> 16);
}
__device__ __forceinline__ float bf2f(unsigned short h) {
  uint32_t u = ((uint32_t)h) << 16;
  return __builtin_bit_cast(float, u);
}

// ============ prep: adj pack (blocks 0..4095) + weight transpose (rest) ====
// Pack bit layout: task t covers row r = t>>5, segment s = t&31 (256 cols).
// Lane l loads float4 at cols s*256 + 4l .. 4l+3. ballot(component q) ->
// word bits[r*128 + s*4 + q], bit l  <->  col = s*256 + 4*l + q.
__global__ __launch_bounds__(256) void prep_kernel(
    const float* __restrict__ adj,
    const float* __restrict__ W1c, const float* __restrict__ W2c,
    const float* __restrict__ W1j, const float* __restrict__ W2j,
    const float* __restrict__ Wl1, const float* __restrict__ Wl2,
    unsigned short* __restrict__ Wt,
    unsigned long long* __restrict__ bits) {
  const int blk = blockIdx.x;
  if (blk < 4096) {
    const float4* __restrict__ adjv = (const float4*)adj;
    const int lane = threadIdx.x & 63;
    const int wv = blk * 4 + (threadIdx.x >> 6);
    const int nwv = 4096 * 4;
    const int total = NN * 32;  // float4-tasks
    // 4 tasks per iter (4 KB in flight per wave); t%4==0 so tasks t..t+3
    // stay within one row => 16 contiguous u64 words to store.
    for (int t = 4 * wv; t < total; t += 4 * nwv) {
      float4 v0 = adjv[(size_t)((t + 0) >> 5) * 2048 + ((t + 0) & 31) * 64 + lane];
      float4 v1 = adjv[(size_t)((t + 1) >> 5) * 2048 + ((t + 1) & 31) * 64 + lane];
      float4 v2 = adjv[(size_t)((t + 2) >> 5) * 2048 + ((t + 2) & 31) * 64 + lane];
      float4 v3 = adjv[(size_t)((t + 3) >> 5) * 2048 + ((t + 3) & 31) * 64 + lane];
      unsigned long long m00 = __ballot(v0.x != 0.0f);
      unsigned long long m01 = __ballot(v0.y != 0.0f);
      unsigned long long m02 = __ballot(v0.z != 0.0f);
      unsigned long long m03 = __ballot(v0.w != 0.0f);
      unsigned long long m10 = __ballot(v1.x != 0.0f);
      unsigned long long m11 = __ballot(v1.y != 0.0f);
      unsigned long long m12 = __ballot(v1.z != 0.0f);
      unsigned long long m13 = __ballot(v1.w != 0.0f);
      unsigned long long m20 = __ballot(v2.x != 0.0f);
      unsigned long long m21 = __ballot(v2.y != 0.0f);
      unsigned long long m22 = __ballot(v2.z != 0.0f);
      unsigned long long m23 = __ballot(v2.w != 0.0f);
      unsigned long long m30 = __ballot(v3.x != 0.0f);
      unsigned long long m31 = __ballot(v3.y != 0.0f);
      unsigned long long m32 = __ballot(v3.z != 0.0f);
      unsigned long long m33 = __ballot(v3.w != 0.0f);
      if (lane == 0) {
        unsigned long long* p = bits + (size_t)(t >> 5) * NW + (t & 31) * 4;
        p[0]  = m00; p[1]  = m01; p[2]  = m02; p[3]  = m03;
        p[4]  = m10; p[5]  = m11; p[6]  = m12; p[7]  = m13;
        p[8]  = m20; p[9]  = m21; p[10] = m22; p[11] = m23;
        p[12] = m30; p[13] = m31; p[14] = m32; p[15] = m33;
      }
    }
  } else {
    // Wt[w][n][k] = W[w][k][n], bf16
    const float* Ws[6] = {W1c, W2c, W1j, W2j, Wl1, Wl2};
    const int b = blk - 4096;
    const int w = b >> 8;
    const int n = b & 255;
    const int k = threadIdx.x;
    Wt[w * 65536 + n * DIM + k] = f2bf(Ws[w][k * DIM + n]);
  }
}

// ================= fused: CN intersect + xixj + 6-GEMM chain + GEMV ========
// Block: 1024 threads = 16 waves, TE=32 edges, 256 blocks (1/CU).
// Each wave owns 16 output cols (1 n-tile) x 2 m-tiles of 16 rows.
// A-frag: row = lane&15, k = (lane>>4)*8 + j
// B-frag: col = lane&15, k = (lane>>4)*8 + j  (register-resident, prefetched)
// C/D:    col = lane&15, row = (lane>>4)*4 + reg   (m89-verified)

#define LDP 264  // 256 + 8 bf16 pad (row stride 528 B, 2-way bank alias = free)

__device__ __forceinline__ void load_w16(const unsigned short* __restrict__ Wt,
                                         bf16x8 w[8], int lane, int wave) {
  const int lr = lane & 15;
  const int kl = (lane >> 4) * 8;
  const int n0 = wave * 16;
#pragma unroll
  for (int kk = 0; kk < 8; ++kk)
    w[kk] = *(const bf16x8*)(Wt + (size_t)(n0 + lr) * DIM + kk * 32 + kl);
}

__device__ __forceinline__ void gemm16(const unsigned short (*src)[LDP],
                                       const bf16x8 w[8],
                                       f32x4 acc[2], int lane) {
  const int lr = lane & 15;
  const int kl = (lane >> 4) * 8;
#pragma unroll
  for (int kk = 0; kk < 8; ++kk) {
    const int k0 = kk * 32 + kl;
    bf16x8 a0 = *(const bf16x8*)(&src[lr][k0]);
    bf16x8 a1 = *(const bf16x8*)(&src[16 + lr][k0]);
    acc[0] = __builtin_amdgcn_mfma_f32_16x16x32_bf16(a0, w[kk], acc[0], 0, 0, 0);
    acc[1] = __builtin_amdgcn_mfma_f32_16x16x32_bf16(a1, w[kk], acc[1], 0, 0, 0);
  }
}

__device__ __forceinline__ void epilogue16(f32x4 acc[2], float bb, bool relu,
                                           unsigned short (*dst)[LDP],
                                           int lane, int wave) {
  const int lc = lane & 15;
  const int rg = (lane >> 4) * 4;
  const int col = wave * 16 + lc;
#pragma unroll
  for (int m = 0; m < 2; ++m)
#pragma unroll
    for (int q = 0; q < 4; ++q) {
      float v = acc[m][q] + bb;
      if (relu) v = fmaxf(v, 0.f);
      dst[m * 16 + rg + q][col] = f2bf(v);
    }
}

__global__ __launch_bounds__(1024) void fused_kernel(
    const float* __restrict__ x,
    const unsigned long long* __restrict__ bits,
    const int* __restrict__ tar,
    const unsigned short* __restrict__ Wt,
    const float* __restrict__ b1c, const float* __restrict__ b2c,
    const float* __restrict__ b1j, const float* __restrict__ b2j,
    const float* __restrict__ bl1, const float* __restrict__ bl2,
    const float* __restrict__ Wout, const float* __restrict__ bout,
    float* __restrict__ out) {
  __shared__ unsigned short lA[TE][LDP];  // xcn -> U2 -> h2
  __shared__ unsigned short lB[TE][LDP];  // U1 -> h -> h3
  __shared__ unsigned short lC[TE][LDP];  // xixj
  __shared__ int hits[TE][HCAP];
  __shared__ int nh[TE];

  const int tid = threadIdx.x;
  const int lane = tid & 63;
  const int wave = tid >> 6;  // 0..15
  const int e0 = blockIdx.x * TE;

  // ---- per-lane constant preloads (biases, Wout) ----
  const int lc = lane & 15;
  const int c0 = wave * 16 + lc;
  const float vb1c = b1c[c0];
  const float vb1j = b1j[c0];
  const float vb2 = b2c[c0] + b2j[c0];
  const float vbl1 = bl1[c0];
  const float vbl2 = bl2[c0];
  const int gpart = tid & 31;  // GEMV: 32 threads/edge, 8 cols each
  float wv[8];
#pragma unroll
  for (int q = 0; q < 8; ++q) wv[q] = Wout[gpart * 8 + q];
  const float vbout = bout[0];

  if (tid < TE) nh[tid] = 0;

  // ---- (a) bits words -> regs (32 thr/edge, 4 words each endpoint) ----
  const int e_a = tid >> 5;
  const int t32 = tid & 31;
  const int ia = tar[e0 + e_a];
  const int ja = tar[NE + e0 + e_a];
  unsigned long long bw_i[4], bw_j[4];
  {
    const unsigned long long* bi = bits + (size_t)ia * NW + t32 * 4;
    const unsigned long long* bj = bits + (size_t)ja * NW + t32 * 4;
#pragma unroll
    for (int q = 0; q < 4; ++q) { bw_i[q] = bi[q]; bw_j[q] = bj[q]; }
  }

  // ---- (b) xixj -> lC (independent; hides (a)'s latency) ----
  {
    const int col = tid & 255;
    const int sub = tid >> 8;  // 0..3 -> 8 edges each
    float vi[8], vj[8];
#pragma unroll
    for (int p = 0; p < 8; ++p) {
      const int e = sub * 8 + p;
      vi[p] = x[(size_t)tar[e0 + e] * DIM + col];
      vj[p] = x[(size_t)tar[NE + e0 + e] * DIM + col];
    }
#pragma unroll
    for (int p = 0; p < 8; ++p)
      lC[sub * 8 + p][col] = f2bf(vi[p] * vj[p]);
  }
  __syncthreads();  // nh zeroed; (a)/(b) loads drained

  // ---- (c) intersect (pure VALU + LDS atomics) ----
  // word w = t32*4+q  ->  base col = t32<<8, node = base + 4*bit + q
#pragma unroll
  for (int q = 0; q < 4; ++q) {
    unsigned long long m = bw_i[q] & bw_j[q];
    const int base = t32 << 8;
    while (m) {
      int b = __builtin_ctzll(m);
      m &= m - 1;
      int idx = atomicAdd(&nh[e_a], 1);
      if (idx < HCAP) hits[e_a][idx] = base + (b << 2) + q;  // node id
    }
  }
  __syncthreads();

  // ---- prefetch S1/S2 weights; xcn gathers -> lA ----
  bf16x8 wX[8], wY[8];
  load_w16(Wt + 0 * 65536, wX, lane, wave);
  load_w16(Wt + 1 * 65536, wY, lane, wave);
  {
    const int col = tid & 255;
    const int sub = tid >> 8;
#pragma unroll
    for (int p = 0; p < 8; ++p) {
      const int e = sub * 8 + p;
      const int n = nh[e] < HCAP ? nh[e] : HCAP;
      float xc = 0.f;
      for (int h = 0; h < n; ++h)
        xc += x[(size_t)hits[e][h] * DIM + col];
      lA[e][col] = f2bf(xc);
    }
  }
  __syncthreads();

  f32x4 acc[2], pAcc[2];
  const f32x4 z4 = {0.f, 0.f, 0.f, 0.f};

  // ---- S1: U1 = relu(xcn @ W1c + b1c) -> lB ; prefetch W1j -> wX ----
  acc[0] = z4; acc[1] = z4;
  gemm16(lA, wX, acc, lane);
  load_w16(Wt + 2 * 65536, wX, lane, wave);
  epilogue16(acc, vb1c, true, lB, lane, wave);
  __syncthreads();

  // ---- S2: pAcc = U1 @ W2c (wY); S3: U2 = relu(xixj @ W1j) -> lA (wX) ----
  pAcc[0] = z4; pAcc[1] = z4;
  gemm16(lB, wY, pAcc, lane);
  load_w16(Wt + 3 * 65536, wY, lane, wave);  // prefetch W2j
  acc[0] = z4; acc[1] = z4;
  gemm16(lC, wX, acc, lane);
  epilogue16(acc, vb1j, true, lA, lane, wave);
  __syncthreads();

  // ---- S4: pAcc += U2 @ W2j (wY); h = pAcc + b2c+b2j -> lB (no relu) ----
  gemm16(lA, wY, pAcc, lane);
  load_w16(Wt + 4 * 65536, wX, lane, wave);  // prefetch Wl1
  {
    const int rg = (lane >> 4) * 4;
    const int col = wave * 16 + lc;
#pragma unroll
    for (int m = 0; m < 2; ++m)
#pragma unroll
      for (int q = 0; q < 4; ++q)
        lB[m * 16 + rg + q][col] = f2bf(pAcc[m][q] + vb2);
  }
  __syncthreads();

  // ---- S5: h2 = relu(h @ Wl1 + bl1) -> lA (wX) ; prefetch Wl2 -> wY ----
  acc[0] = z4; acc[1] = z4;
  gemm16(lB, wX, acc, lane);
  load_w16(Wt + 5 * 65536, wY, lane, wave);
  epilogue16(acc, vbl1, true, lA, lane, wave);
  __syncthreads();

  // ---- S6: h3 = relu(h2 @ Wl2 + bl2) -> lB (wY) ----
  acc[0] = z4; acc[1] = z4;
  gemm16(lA, wY, acc, lane);
  epilogue16(acc, vbl2, true, lB, lane, wave);
  __syncthreads();

  // ---- GEMV: out = h3 @ Wout + bout (32 threads/edge, preloaded Wout) ----
  const int el = tid >> 5;
  float s = 0.f;
#pragma unroll
  for (int q = 0; q < 8; ++q)
    s += bf2f(lB[el][gpart * 8 + q]) * wv[q];
#pragma unroll
  for (int o = 16; o; o >>= 1) s += __shfl_xor(s, o);
  if (gpart == 0) out[e0 + el] = s + vbout;
}

extern "C" void kernel_launch(void* const* d_in, const int* in_sizes, int n_in,
                              void* d_out, int out_size, void* d_ws, size_t ws_size,
                              hipStream_t stream) {
  const float* x    = (const float*)d_in[0];
  const float* adj  = (const float*)d_in[1];
  const int*   tar  = (const int*)d_in[2];
  const float* W1c  = (const float*)d_in[3];
  const float* b1c  = (const float*)d_in[4];
  const float* W2c  = (const float*)d_in[5];
  const float* b2c  = (const float*)d_in[6];
  const float* W1j  = (const float*)d_in[7];
  const float* b1j  = (const float*)d_in[8];
  const float* W2j  = (const float*)d_in[9];
  const float* b2j  = (const float*)d_in[10];
  const float* Wl1  = (const float*)d_in[11];
  const float* bl1  = (const float*)d_in[12];
  const float* Wl2  = (const float*)d_in[13];
  const float* bl2  = (const float*)d_in[14];
  const float* Wout = (const float*)d_in[15];
  const float* bout = (const float*)d_in[16];

  char* ws = (char*)d_ws;
  unsigned short*     Wt   = (unsigned short*)(ws);                  // 768 KB
  unsigned long long* bits = (unsigned long long*)(ws + (1u << 20)); // 8 MB

  prep_kernel<<<4096 + 1536, 256, 0, stream>>>(adj, W1c, W2c, W1j, W2j, Wl1,
                                               Wl2, Wt, bits);

  fused_kernel<<<NE / TE, 1024, 0, stream>>>(x, bits, tar, Wt, b1c, b2c, b1j,
                                             b2j, bl1, bl2, Wout, bout,
                                             (float*)d_out);
}